// Round 1
// baseline (59.627 us; speedup 1.0000x reference)
//
#include <hip/hip_runtime.h>

#define N_IN 512
#define N_VP 12
#define BATCH 65536

// ---------------------------------------------------------------------------
// Kernel A (1 block, 512 threads, runs once): build W = phi * Ginv^T  [512][12]
//   phi[n][k]: weighted Hermite functions at xs = dil*(t - tr), t = n - 255.5
//   G = phi^T phi  (~10*I, SPD, well-conditioned) -> fp64 Gauss-Jordan inverse
//   W[n][k] = sum_j Ginv[k][j] * phi[n][j]   so  out = x @ W
// ---------------------------------------------------------------------------
__global__ __launch_bounds__(512) void build_W_kernel(const float* __restrict__ w,
                                                      float* __restrict__ Wg) {
    __shared__ float  sphi[N_IN * N_VP];          // 24 KB
    __shared__ double A[N_VP][2 * N_VP];          // augmented [G | I] -> [I | Ginv]

    const int tid = threadIdx.x;
    const float dil = w[0];
    const float tr  = w[1];

    // per-thread phi row (n = tid)
    float p[N_VP];
    {
        const float t  = (float)tid - 0.5f * (float)(N_IN - 1);
        const float xs = dil * (t - tr);
        p[0] = 0.7511255444649425f * expf(-0.5f * xs * xs);   // pi^-1/4 * gaussian
        p[1] = 1.4142135623730951f * xs * p[0];
#pragma unroll
        for (int k = 2; k < N_VP; ++k) {
            const float a = sqrtf(2.0f / (float)k);
            const float b = sqrtf((float)(k - 1) / (float)k);
            p[k] = a * xs * p[k - 1] - b * p[k - 2];
        }
#pragma unroll
        for (int k = 0; k < N_VP; ++k) sphi[tid * N_VP + k] = p[k];
    }
    __syncthreads();

    // G (fp64 accumulate) + identity into augmented A
    if (tid < N_VP * N_VP) {
        const int i = tid / N_VP, j = tid % N_VP;
        double s0 = 0.0, s1 = 0.0, s2 = 0.0, s3 = 0.0;
        for (int m = 0; m < N_IN; m += 4) {
            s0 += (double)sphi[(m + 0) * N_VP + i] * (double)sphi[(m + 0) * N_VP + j];
            s1 += (double)sphi[(m + 1) * N_VP + i] * (double)sphi[(m + 1) * N_VP + j];
            s2 += (double)sphi[(m + 2) * N_VP + i] * (double)sphi[(m + 2) * N_VP + j];
            s3 += (double)sphi[(m + 3) * N_VP + i] * (double)sphi[(m + 3) * N_VP + j];
        }
        A[i][j]        = (s0 + s1) + (s2 + s3);
        A[i][N_VP + j] = (i == j) ? 1.0 : 0.0;
    }
    __syncthreads();

    // parallel Gauss-Jordan, no pivoting (diag ~ 10, SPD)
    const int r  = tid / (2 * N_VP);   // row    (valid for tid < 288)
    const int c2 = tid % (2 * N_VP);   // column
    for (int c = 0; c < N_VP; ++c) {
        __syncthreads();
        const double pivinv = 1.0 / A[c][c];       // read-only phase
        __syncthreads();
        if (tid < 2 * N_VP) A[c][tid] *= pivinv;   // scale pivot row
        __syncthreads();
        double f = 0.0;
        if (tid < N_VP * 2 * N_VP) f = A[r][c];    // snapshot factors
        __syncthreads();
        if (tid < N_VP * 2 * N_VP && r != c) A[r][c2] -= f * A[c][c2];
    }
    __syncthreads();

    // W[n][k] = sum_j Ginv[k][j] * phi[n][j]
#pragma unroll
    for (int k = 0; k < N_VP; ++k) {
        double s = 0.0;
#pragma unroll
        for (int j = 0; j < N_VP; ++j) s += A[k][N_VP + j] * (double)p[j];
        Wg[tid * N_VP + k] = (float)s;
    }
}

// ---------------------------------------------------------------------------
// Kernel B: out[row][k] = sum_n x[row][n] * W[n][k]
//   1 thread = 1 row. W accessed with wave-uniform indices -> compiler emits
//   s_load into SGPRs (scalar pipe, free wrt VALU/VMEM); x via float4 loads.
// ---------------------------------------------------------------------------
__global__ __launch_bounds__(256) void coeffs_kernel(const float* __restrict__ x,
                                                     const float* __restrict__ Wg,
                                                     float* __restrict__ out) {
    const int row = blockIdx.x * blockDim.x + threadIdx.x;
    const float4* __restrict__ xr =
        reinterpret_cast<const float4*>(x + (size_t)row * N_IN);

    float acc[N_VP];
#pragma unroll
    for (int k = 0; k < N_VP; ++k) acc[k] = 0.0f;

#pragma unroll 4
    for (int n4 = 0; n4 < N_IN / 4; ++n4) {
        const float4 xv = xr[n4];
        const float* __restrict__ wp = Wg + n4 * (4 * N_VP);
#pragma unroll
        for (int k = 0; k < N_VP; ++k) acc[k] = fmaf(xv.x, wp[k], acc[k]);
#pragma unroll
        for (int k = 0; k < N_VP; ++k) acc[k] = fmaf(xv.y, wp[N_VP + k], acc[k]);
#pragma unroll
        for (int k = 0; k < N_VP; ++k) acc[k] = fmaf(xv.z, wp[2 * N_VP + k], acc[k]);
#pragma unroll
        for (int k = 0; k < N_VP; ++k) acc[k] = fmaf(xv.w, wp[3 * N_VP + k], acc[k]);
    }

    float4* orow = reinterpret_cast<float4*>(out + (size_t)row * N_VP);
    orow[0] = make_float4(acc[0], acc[1], acc[2],  acc[3]);
    orow[1] = make_float4(acc[4], acc[5], acc[6],  acc[7]);
    orow[2] = make_float4(acc[8], acc[9], acc[10], acc[11]);
}

extern "C" void kernel_launch(void* const* d_in, const int* in_sizes, int n_in,
                              void* d_out, int out_size, void* d_ws, size_t ws_size,
                              hipStream_t stream) {
    const float* x  = (const float*)d_in[0];   // [65536, 512] fp32
    const float* w  = (const float*)d_in[1];   // [2] fp32
    float* out      = (float*)d_out;           // [65536, 12] fp32
    float* Wg       = (float*)d_ws;            // [512, 12] fp32 scratch

    build_W_kernel<<<1, 512, 0, stream>>>(w, Wg);
    coeffs_kernel<<<BATCH / 256, 256, 0, stream>>>(x, Wg, out);
}